// Round 3
// baseline (708.803 us; speedup 1.0000x reference)
//
#include <hip/hip_runtime.h>
#include <hip/hip_bf16.h>
#include <stdint.h>

typedef __bf16 bf16x8 __attribute__((ext_vector_type(8)));
typedef float  f32x4  __attribute__((ext_vector_type(4)));
typedef unsigned short u16x8 __attribute__((ext_vector_type(8)));

// ---- helpers ---------------------------------------------------------------

__device__ __forceinline__ unsigned short f32_to_bf16_rne(float f) {
  union { float f; unsigned int u; } v; v.f = f;
  unsigned int u = v.u;
  unsigned int r = u + 0x7fffu + ((u >> 16) & 1u);  // round-to-nearest-even
  return (unsigned short)(r >> 16);
}

// async global->LDS, 16B per lane. LDS dest is wave-uniform base; HW scatters
// lane i at base + i*16 (guide §5 caveat, m104/m108).
__device__ __forceinline__ void async16(const unsigned short* g, unsigned short* l) {
  __builtin_amdgcn_global_load_lds(
      (const __attribute__((address_space(1))) unsigned int*)g,
      (__attribute__((address_space(3))) unsigned int*)l,
      16, 0, 0);
}

// ---- kernel 1: W' = W + 2*(lora_B @ lora_A), cast to bf16 ------------------
// v2: 8 rows/thread so the 16 lA float4 register-loads amortize over 8 W rows.
// lB[o*16+r] is blockIdx-derived (wave-uniform) -> scalar loads, free operands.
// VMEM instr: 1 per output element (was 4.25) -> instruction-issue floor ~25us.
__global__ __launch_bounds__(256) void make_wp(const float* __restrict__ W,
                                               const float* __restrict__ lA,
                                               const float* __restrict__ lB,
                                               unsigned short* __restrict__ Wp) {
  const int ro = (blockIdx.x & 511) * 8;        // row group: 8 rows
  const int k  = (blockIdx.x >> 9) * 1024 + threadIdx.x * 4;  // k strip

  float4 a[16];
  #pragma unroll
  for (int r = 0; r < 16; ++r)
    a[r] = *(const float4*)(lA + (size_t)r * 4096 + k);

  #pragma unroll
  for (int i = 0; i < 8; ++i) {
    const int o = ro + i;
    float4 acc = *(const float4*)(W + (size_t)o * 4096 + k);
    #pragma unroll
    for (int r = 0; r < 16; ++r) {
      const float s = lB[o * 16 + r] * 2.0f;   // wave-uniform -> s_load
      acc.x += s * a[r].x; acc.y += s * a[r].y;
      acc.z += s * a[r].z; acc.w += s * a[r].w;
    }
    ushort4 ov;
    ov.x = f32_to_bf16_rne(acc.x);
    ov.y = f32_to_bf16_rne(acc.y);
    ov.z = f32_to_bf16_rne(acc.z);
    ov.w = f32_to_bf16_rne(acc.w);
    *(ushort4*)(Wp + (size_t)o * 4096 + k) = ov;
  }
}

// ---- kernel 2: out[M,N] = x_f32[M,K] @ Wp[N,K]^T + bias --------------------
// m97 structure: 128x128 tile, BK=32, 4 waves 2x2, 4x4 16x16x32 bf16 frags,
// 2-barrier K-loop. B staged via async16 from bf16 Wp; A staged directly from
// f32 x: global_load_dwordx4 x2 -> RNE cvt -> ds_write_b128 into the SAME
// bf16 LDS layout the async16 path would produce (verified identical map).
#define BM 128
#define BN 128
#define BK 32
#define GEMM_M 8192
#define GEMM_N 4096
#define GEMM_K 4096

__global__ __launch_bounds__(256) void gemm_bias(
    const float* __restrict__ A,            // [M,K] f32 (x)
    const unsigned short* __restrict__ B,   // [N,K] bf16 bits (Wp)
    const float* __restrict__ bias,         // [N]
    float* __restrict__ C) {                // [M,N] fp32
  // LDS tiles: [128 rows][32 k] bf16, contiguous, NO padding (async16 scatter
  // order == lane order; the ds_write path mirrors the same layout exactly).
  __shared__ __align__(16) unsigned short sA[BM * BK];
  __shared__ __align__(16) unsigned short sB[BM * BK];

  const int tid  = threadIdx.x;
  const int wave = tid >> 6;
  const int lane = tid & 63;

  // staging map: thread tid -> row tid>>2 (0..63), col (tid&3)*8 bf16 elems;
  // LDS offset == tid*8 shorts within each 64-row half.
  const int srow = tid >> 2;
  const int scol = (tid & 3) << 3;

  const size_t a_row0 = (size_t)blockIdx.y * BM;
  const size_t b_row0 = (size_t)blockIdx.x * BN;

  const unsigned short* bg0 = B + (b_row0 +      srow) * GEMM_K + scol;
  const unsigned short* bg1 = B + (b_row0 + 64 + srow) * GEMM_K + scol;
  const float*          af0 = A + (a_row0 +      srow) * GEMM_K + scol;
  const float*          af1 = A + (a_row0 + 64 + srow) * GEMM_K + scol;

  // wave-uniform LDS bases for async16 (wave w: lanes land at base + lane*16B)
  unsigned short* sB0 = sB +        wave * 512;
  unsigned short* sB1 = sB + 2048 + wave * 512;
  // per-thread ds_write dests (same layout as async16 would give)
  unsigned short* sAw0 = sA +        tid * 8;
  unsigned short* sAw1 = sA + 2048 + tid * 8;

  // compute-phase map: wave (wm,wn) 2x2, 64x64 per wave
  const int wm   = (wave >> 1) * 64;
  const int wn   = (wave & 1) * 64;
  const int lrow = lane & 15;
  const int lk   = (lane >> 4) * 8;

  const unsigned short* sa_rd = sA + (wm + lrow) * BK + lk;
  const unsigned short* sb_rd = sB + (wn + lrow) * BK + lk;

  f32x4 acc[4][4];
  #pragma unroll
  for (int i = 0; i < 4; ++i)
    #pragma unroll
    for (int j = 0; j < 4; ++j)
      acc[i][j] = (f32x4){0.f, 0.f, 0.f, 0.f};

  for (int k0 = 0; k0 < GEMM_K; k0 += BK) {
    __syncthreads();   // prior iter's LDS reads done before overwrite
    async16(bg0 + k0, sB0);
    async16(bg1 + k0, sB1);
    {
      const float* p0 = af0 + k0;
      const float* p1 = af1 + k0;
      const float4 x0 = *(const float4*)(p0);
      const float4 x1 = *(const float4*)(p0 + 4);
      const float4 y0 = *(const float4*)(p1);
      const float4 y1 = *(const float4*)(p1 + 4);
      u16x8 w0, w1;
      w0[0] = f32_to_bf16_rne(x0.x); w0[1] = f32_to_bf16_rne(x0.y);
      w0[2] = f32_to_bf16_rne(x0.z); w0[3] = f32_to_bf16_rne(x0.w);
      w0[4] = f32_to_bf16_rne(x1.x); w0[5] = f32_to_bf16_rne(x1.y);
      w0[6] = f32_to_bf16_rne(x1.z); w0[7] = f32_to_bf16_rne(x1.w);
      w1[0] = f32_to_bf16_rne(y0.x); w1[1] = f32_to_bf16_rne(y0.y);
      w1[2] = f32_to_bf16_rne(y0.z); w1[3] = f32_to_bf16_rne(y0.w);
      w1[4] = f32_to_bf16_rne(y1.x); w1[5] = f32_to_bf16_rne(y1.y);
      w1[6] = f32_to_bf16_rne(y1.z); w1[7] = f32_to_bf16_rne(y1.w);
      *(u16x8*)sAw0 = w0;   // ds_write_b128
      *(u16x8*)sAw1 = w1;
    }
    __syncthreads();   // compiler drains vmcnt/lgkmcnt before s_barrier

    bf16x8 af[4], bf[4];
    #pragma unroll
    for (int i = 0; i < 4; ++i) {
      af[i] = *(const bf16x8*)(sa_rd + i * 16 * BK);
      bf[i] = *(const bf16x8*)(sb_rd + i * 16 * BK);
    }
    #pragma unroll
    for (int i = 0; i < 4; ++i)
      #pragma unroll
      for (int j = 0; j < 4; ++j)
        acc[i][j] = __builtin_amdgcn_mfma_f32_16x16x32_bf16(af[i], bf[j], acc[i][j], 0, 0, 0);
  }

  // epilogue: C/D layout col=lane&15, row=(lane>>4)*4+reg (m89-verified)
  const int row0 = (int)a_row0 + wm + (lane >> 4) * 4;
  const int col0 = (int)b_row0 + wn + lrow;
  float bv[4];
  #pragma unroll
  for (int j = 0; j < 4; ++j) bv[j] = bias[col0 + j * 16];
  #pragma unroll
  for (int i = 0; i < 4; ++i)
    #pragma unroll
    for (int j = 0; j < 4; ++j) {
      const int col = col0 + j * 16;
      #pragma unroll
      for (int r = 0; r < 4; ++r) {
        const int row = row0 + i * 16 + r;
        C[(size_t)row * GEMM_N + col] = acc[i][j][r] + bv[j];
      }
    }
}

// ---- launch ----------------------------------------------------------------

extern "C" void kernel_launch(void* const* d_in, const int* in_sizes, int n_in,
                              void* d_out, int out_size, void* d_ws, size_t ws_size,
                              hipStream_t stream) {
  const float* x  = (const float*)d_in[0];   // [4,2048,4096]
  const float* W  = (const float*)d_in[1];   // [4096,4096]
  const float* b  = (const float*)d_in[2];   // [4096]
  const float* lA = (const float*)d_in[3];   // [16,4096]
  const float* lB = (const float*)d_in[4];   // [4096,16]
  float* out = (float*)d_out;                // [4,2048,4096] fp32
  (void)in_sizes; (void)n_in; (void)out_size; (void)ws_size;

  // ws: only Wp bf16 [4096*4096] = 32 MiB. No xb, no ws_size branch — the
  // GEMM stages f32 x directly (round-1 OOB lesson: never assume big ws).
  unsigned short* Wp = (unsigned short*)d_ws;

  // grid: 512 row-groups (8 rows) x 4 k-chunks (1024 floats)
  make_wp<<<2048, 256, 0, stream>>>(W, lA, lB, Wp);
  gemm_bias<<<dim3(GEMM_N / BN, GEMM_M / BM), 256, 0, stream>>>(x, Wp, b, out);
}

// Round 4
// 578.811 us; speedup vs baseline: 1.2246x; 1.2246x over previous
//
#include <hip/hip_runtime.h>
#include <hip/hip_bf16.h>
#include <stdint.h>

typedef __bf16 bf16x8 __attribute__((ext_vector_type(8)));
typedef float  f32x4  __attribute__((ext_vector_type(4)));
typedef unsigned short u16x8 __attribute__((ext_vector_type(8)));

// ---- helpers ---------------------------------------------------------------

__device__ __forceinline__ unsigned short f32_to_bf16_rne(float f) {
  union { float f; unsigned int u; } v; v.f = f;
  unsigned int u = v.u;
  unsigned int r = u + 0x7fffu + ((u >> 16) & 1u);  // round-to-nearest-even
  return (unsigned short)(r >> 16);
}

// async global->LDS, 16B per lane. LDS dest is wave-uniform base; HW scatters
// lane i at base + i*16 (guide §5 caveat, m104/m108).
__device__ __forceinline__ void async16(const unsigned short* g, unsigned short* l) {
  __builtin_amdgcn_global_load_lds(
      (const __attribute__((address_space(1))) unsigned int*)g,
      (__attribute__((address_space(3))) unsigned int*)l,
      16, 0, 0);
}

// ---- kernel 1 (fused): W' = W + 2*(lora_B@lora_A) -> bf16 ; x -> bf16 ------
// blocks [0,2048): make_wp v2 — 8 rows/thread, 16 lA float4s held in regs,
//   lB scalar (wave-uniform). VMEM ~1 instr/output.
// blocks [2048,6144): cast x, 32 elems/thread, coalesced per-iteration.
// Both parts are pure streaming; fusing overlaps them and saves a dispatch.
__global__ __launch_bounds__(256) void prep_fused(const float* __restrict__ W,
                                                  const float* __restrict__ lA,
                                                  const float* __restrict__ lB,
                                                  const float* __restrict__ x,
                                                  unsigned short* __restrict__ Wp,
                                                  unsigned short* __restrict__ xb) {
  const int b   = blockIdx.x;
  const int tid = threadIdx.x;
  if (b < 2048) {
    const int ro = (b & 511) * 8;                    // row group: 8 rows
    const int k  = (b >> 9) * 1024 + tid * 4;        // k strip
    float4 a[16];
    #pragma unroll
    for (int r = 0; r < 16; ++r)
      a[r] = *(const float4*)(lA + (size_t)r * 4096 + k);
    #pragma unroll
    for (int i = 0; i < 8; ++i) {
      const int o = ro + i;
      float4 acc = *(const float4*)(W + (size_t)o * 4096 + k);
      #pragma unroll
      for (int r = 0; r < 16; ++r) {
        const float s = lB[o * 16 + r] * 2.0f;       // wave-uniform -> s_load
        acc.x += s * a[r].x; acc.y += s * a[r].y;
        acc.z += s * a[r].z; acc.w += s * a[r].w;
      }
      ushort4 ov;
      ov.x = f32_to_bf16_rne(acc.x);
      ov.y = f32_to_bf16_rne(acc.y);
      ov.z = f32_to_bf16_rne(acc.z);
      ov.w = f32_to_bf16_rne(acc.w);
      *(ushort4*)(Wp + (size_t)o * 4096 + k) = ov;
    }
  } else {
    // cast: 4096 blocks x 256 thr x 4 iters x 8 elems = 33.55M elems
    const int cb = b - 2048;
    #pragma unroll
    for (int it = 0; it < 4; ++it) {
      const size_t g8 = (size_t)cb * 1024 + it * 256 + tid;  // group-of-8 idx
      const float4* p = (const float4*)x + g8 * 2;
      const float4 f0 = p[0], f1 = p[1];
      u16x8 o;
      o[0] = f32_to_bf16_rne(f0.x); o[1] = f32_to_bf16_rne(f0.y);
      o[2] = f32_to_bf16_rne(f0.z); o[3] = f32_to_bf16_rne(f0.w);
      o[4] = f32_to_bf16_rne(f1.x); o[5] = f32_to_bf16_rne(f1.y);
      o[6] = f32_to_bf16_rne(f1.z); o[7] = f32_to_bf16_rne(f1.w);
      *((u16x8*)xb + g8) = o;
    }
  }
}

// ---- kernel 2: out[M,N] = A[M,K] @ Wp[N,K]^T + bias ------------------------
// Byte-identical structure to the round-2 kernel that passed at 344us:
// m97 structure, 128x128 tile, BK=32, 4 waves 2x2, 4x4 16x16x32 bf16 frags.
// A_F32=false: bf16 A via async16 (fast path, needs 96MiB ws).
// A_F32=true: f32 A staged via cvt+ds_write (fallback; proven correct R3).
#define BM 128
#define BN 128
#define BK 32
#define GEMM_M 8192
#define GEMM_N 4096
#define GEMM_K 4096

template <bool A_F32>
__global__ __launch_bounds__(256) void gemm_bias(
    const void* __restrict__ Aptr,          // [M,K] bf16 bits or f32
    const unsigned short* __restrict__ B,   // [N,K] bf16 bits (Wp)
    const float* __restrict__ bias,         // [N]
    float* __restrict__ C) {                // [M,N] fp32
  __shared__ __align__(16) unsigned short sA[BM * BK];
  __shared__ __align__(16) unsigned short sB[BM * BK];

  const int tid  = threadIdx.x;
  const int wave = tid >> 6;
  const int lane = tid & 63;

  const int srow = tid >> 2;            // 0..63
  const int scol = (tid & 3) << 3;      // 0,8,16,24 bf16 elems

  const size_t a_row0 = (size_t)blockIdx.y * BM;
  const size_t b_row0 = (size_t)blockIdx.x * BN;

  const unsigned short* bg0 = B + (b_row0 +      srow) * GEMM_K + scol;
  const unsigned short* bg1 = B + (b_row0 + 64 + srow) * GEMM_K + scol;

  unsigned short* sA0 = sA +        wave * 512;
  unsigned short* sA1 = sA + 2048 + wave * 512;
  unsigned short* sB0 = sB +        wave * 512;
  unsigned short* sB1 = sB + 2048 + wave * 512;

  const unsigned short* ag0 = nullptr; const unsigned short* ag1 = nullptr;
  const float* af0 = nullptr; const float* af1 = nullptr;
  if constexpr (A_F32) {
    af0 = (const float*)Aptr + (a_row0 +      srow) * GEMM_K + scol;
    af1 = (const float*)Aptr + (a_row0 + 64 + srow) * GEMM_K + scol;
  } else {
    ag0 = (const unsigned short*)Aptr + (a_row0 +      srow) * GEMM_K + scol;
    ag1 = (const unsigned short*)Aptr + (a_row0 + 64 + srow) * GEMM_K + scol;
  }
  unsigned short* sAw0 = sA +        tid * 8;
  unsigned short* sAw1 = sA + 2048 + tid * 8;

  const int wm   = (wave >> 1) * 64;
  const int wn   = (wave & 1) * 64;
  const int lrow = lane & 15;
  const int lk   = (lane >> 4) * 8;

  const unsigned short* sa_rd = sA + (wm + lrow) * BK + lk;
  const unsigned short* sb_rd = sB + (wn + lrow) * BK + lk;

  f32x4 acc[4][4];
  #pragma unroll
  for (int i = 0; i < 4; ++i)
    #pragma unroll
    for (int j = 0; j < 4; ++j)
      acc[i][j] = (f32x4){0.f, 0.f, 0.f, 0.f};

  for (int k0 = 0; k0 < GEMM_K; k0 += BK) {
    __syncthreads();
    async16(bg0 + k0, sB0);
    async16(bg1 + k0, sB1);
    if constexpr (A_F32) {
      const float* p0 = af0 + k0;
      const float* p1 = af1 + k0;
      const float4 x0 = *(const float4*)(p0);
      const float4 x1 = *(const float4*)(p0 + 4);
      const float4 y0 = *(const float4*)(p1);
      const float4 y1 = *(const float4*)(p1 + 4);
      u16x8 w0, w1;
      w0[0] = f32_to_bf16_rne(x0.x); w0[1] = f32_to_bf16_rne(x0.y);
      w0[2] = f32_to_bf16_rne(x0.z); w0[3] = f32_to_bf16_rne(x0.w);
      w0[4] = f32_to_bf16_rne(x1.x); w0[5] = f32_to_bf16_rne(x1.y);
      w0[6] = f32_to_bf16_rne(x1.z); w0[7] = f32_to_bf16_rne(x1.w);
      w1[0] = f32_to_bf16_rne(y0.x); w1[1] = f32_to_bf16_rne(y0.y);
      w1[2] = f32_to_bf16_rne(y0.z); w1[3] = f32_to_bf16_rne(y0.w);
      w1[4] = f32_to_bf16_rne(y1.x); w1[5] = f32_to_bf16_rne(y1.y);
      w1[6] = f32_to_bf16_rne(y1.z); w1[7] = f32_to_bf16_rne(y1.w);
      *(u16x8*)sAw0 = w0;
      *(u16x8*)sAw1 = w1;
    } else {
      async16(ag0 + k0, sA0);
      async16(ag1 + k0, sA1);
    }
    __syncthreads();

    bf16x8 af[4], bf[4];
    #pragma unroll
    for (int i = 0; i < 4; ++i) {
      af[i] = *(const bf16x8*)(sa_rd + i * 16 * BK);
      bf[i] = *(const bf16x8*)(sb_rd + i * 16 * BK);
    }
    #pragma unroll
    for (int i = 0; i < 4; ++i)
      #pragma unroll
      for (int j = 0; j < 4; ++j)
        acc[i][j] = __builtin_amdgcn_mfma_f32_16x16x32_bf16(af[i], bf[j], acc[i][j], 0, 0, 0);
  }

  // epilogue: C/D layout col=lane&15, row=(lane>>4)*4+reg (m89-verified)
  const int row0 = (int)a_row0 + wm + (lane >> 4) * 4;
  const int col0 = (int)b_row0 + wn + lrow;
  float bv[4];
  #pragma unroll
  for (int j = 0; j < 4; ++j) bv[j] = bias[col0 + j * 16];
  #pragma unroll
  for (int i = 0; i < 4; ++i)
    #pragma unroll
    for (int j = 0; j < 4; ++j) {
      const int col = col0 + j * 16;
      #pragma unroll
      for (int r = 0; r < 4; ++r) {
        const int row = row0 + i * 16 + r;
        C[(size_t)row * GEMM_N + col] = acc[i][j][r] + bv[j];
      }
    }
}

// ---- launch ----------------------------------------------------------------

extern "C" void kernel_launch(void* const* d_in, const int* in_sizes, int n_in,
                              void* d_out, int out_size, void* d_ws, size_t ws_size,
                              hipStream_t stream) {
  const float* x  = (const float*)d_in[0];   // [4,2048,4096]
  const float* W  = (const float*)d_in[1];   // [4096,4096]
  const float* b  = (const float*)d_in[2];   // [4096]
  const float* lA = (const float*)d_in[3];   // [16,4096]
  const float* lB = (const float*)d_in[4];   // [4096,16]
  float* out = (float*)d_out;                // [4,2048,4096] fp32
  (void)in_sizes; (void)n_in; (void)out_size;

  // ws: Wp bf16 32MiB; fast path adds xb bf16 64MiB. Branch on ws_size
  // (constant per session -> same work every call; R2 proved fast branch runs
  // and passes on this harness).
  const size_t WP_BYTES = (size_t)4096 * 4096 * 2;
  const size_t XB_BYTES = (size_t)8192 * 4096 * 2;
  unsigned short* Wp = (unsigned short*)d_ws;

  if (ws_size >= WP_BYTES + XB_BYTES) {
    unsigned short* xb = Wp + (size_t)4096 * 4096;
    prep_fused<<<6144, 256, 0, stream>>>(W, lA, lB, x, Wp, xb);
    gemm_bias<false><<<dim3(GEMM_N / BN, GEMM_M / BM), 256, 0, stream>>>(
        (const void*)xb, Wp, b, out);
  } else {
    prep_fused<<<2048, 256, 0, stream>>>(W, lA, lB, x, Wp, (unsigned short*)nullptr);
    gemm_bias<true><<<dim3(GEMM_N / BN, GEMM_M / BM), 256, 0, stream>>>(
        (const void*)x, Wp, b, out);
  }
}